// Round 20
// baseline (132.011 us; speedup 1.0000x reference)
//
#include <hip/hip_runtime.h>
#include <hip/hip_bf16.h>
#include <math.h>

typedef __bf16 bf16x8 __attribute__((ext_vector_type(8)));
typedef __bf16 bf16x4 __attribute__((ext_vector_type(4)));
typedef float  f32x4  __attribute__((ext_vector_type(4)));

#define NND 8192
#define DIM 64
#define PB  10368   // l2bf padded row stride (bf16)

__device__ __forceinline__ float wsum(float v) {
#pragma unroll
    for (int m = 1; m < 64; m <<= 1) v += __shfl_xor(v, m, 64);
    return v;
}

struct SC { float sh, ch; };
__device__ __forceinline__ SC sinhcosh(float c) {
    float e  = expf(c);
    float ei = 1.0f / e;
    SC r; r.sh = 0.5f * (e - ei); r.ch = 0.5f * (e + ei);
    return r;
}

__device__ __forceinline__ float arcosh_from_n2(float n2) {
    float t = fmaxf(n2, 2.0000001e-7f);
    return logf(sqrtf(1.0f + t) + sqrtf(t));
}

__device__ __forceinline__ float tangent_chain(float xv, int lane) {
    float y   = (lane == 0) ? 0.0f : xv;
    float yn2 = wsum(y * y);
    float yn  = fmaxf(sqrtf(fmaxf(yn2, 1e-30f)), 1e-15f);
    SC s1 = sinhcosh(fminf(yn, 15.0f));
    float r   = (lane == 0) ? 0.0f : s1.sh * y / yn;
    float rn2 = wsum(r * r);
    float ynb = fmaxf(sqrtf(fmaxf(rn2, 1e-30f)), 1e-15f);
    float ac  = arcosh_from_n2(rn2);
    return (lane == 0) ? 0.0f : ac * r / ynb;
}

__device__ __forceinline__ float second_chain(float m, float ubv, float theta_b, int lane) {
    float my  = (lane == 0) ? 0.0f : m;
    float mn2 = wsum(my * my);
    float mn  = fmaxf(sqrtf(fmaxf(mn2, 1e-30f)), 1e-15f);
    SC s2 = sinhcosh(fminf(mn, 15.0f));
    float rr   = (lane == 0) ? 0.0f : s2.sh * my / mn;
    float rrn2 = wsum(rr * rr);
    float res0 = sqrtf(fmaxf(1.0f + rrn2, 1e-7f));
    float yn3   = fmaxf(sqrtf(fmaxf(rrn2, 1e-30f)), 1e-15f);
    float yhat  = (lane == 0) ? 0.0f : rr / yn3;
    float alpha = wsum(yhat * ubv);
    float w_    = ubv - alpha * (1.0f - res0) * yhat;
    float ux    = wsum(rr * w_);
    float v0    = ux / fmaxf(res0, 1e-7f);
    float vv    = (lane == 0) ? v0 : w_;
    float resv  = (lane == 0) ? res0 : rr;
    float theta = theta_b;
    SC s3 = sinhcosh(fminf(theta, 15.0f));
    float pv  = s3.ch * resv + s3.sh * vv / theta;
    float pn2 = wsum((lane == 0) ? 0.0f : pv * pv);
    float yn4 = fmaxf(sqrtf(fmaxf(pn2, 1e-30f)), 1e-15f);
    float ac4 = arcosh_from_n2(pn2);
    return (lane == 0) ? 0.0f : ac4 * pv / yn4;
}

__device__ __forceinline__ float epilogue_chain(float hv, int lane) {
    float y   = (lane == 0) ? 0.0f : hv;
    float yn2 = wsum(y * y);
    float yn  = fmaxf(sqrtf(fmaxf(yn2, 1e-30f)), 1e-15f);
    SC s1 = sinhcosh(fminf(yn, 15.0f));
    float r   = (lane == 0) ? 0.0f : s1.sh * y / yn;
    float rn2 = wsum(r * r);
    float ynb = fmaxf(sqrtf(fmaxf(rn2, 1e-30f)), 1e-15f);
    float ac  = arcosh_from_n2(rn2);
    float lgv = (lane == 0) ? 0.0f : ac * r / ynb;
    float t   = (lgv > 0.0f) ? lgv : 0.01f * lgv;
    float tn2 = wsum(t * t);
    float tn  = fmaxf(sqrtf(fmaxf(tn2, 1e-30f)), 1e-15f);
    SC s3 = sinhcosh(fminf(tn, 15.0f));
    float ov  = (lane == 0) ? 0.0f : s3.sh * t / tn;
    float on2 = wsum(ov * ov);
    float o0  = sqrtf(fmaxf(1.0f + on2, 1e-7f));
    return (lane == 0) ? o0 : ov;
}

// Kernel 1: per-row chain + 64x64 matvec; 1 row per wave. (PB layout, unchanged)
__global__ __launch_bounds__(256) void k_prep(
    const float* __restrict__ x, const float* __restrict__ weight,
    const float* __restrict__ bias, __bf16* __restrict__ l2bf)
{
    __shared__ float WL[64][65];
    const int tid  = threadIdx.x;
    const int lane = tid & 63;
    const int wave = tid >> 6;
#pragma unroll
    for (int i = 0; i < 16; ++i) {
        int idx = i * 256 + tid;
        WL[idx >> 6][idx & 63] = weight[idx];
    }
    __syncthreads();
    float ubv  = tangent_chain(bias[lane], lane);
    float nub2 = wsum(ubv * ubv);
    float thb  = fmaxf(fminf(sqrtf(fmaxf(nub2, 1e-7f)), 1e6f), 1e-15f);

    const int row = blockIdx.x * 4 + wave;
    float xv  = x[row * 64 + lane];
    float L1v = tangent_chain(xv, lane);
    float mj0 = 0.f, mj1 = 0.f, mj2 = 0.f, mj3 = 0.f;
#pragma unroll
    for (int d = 0; d < 64; d += 4) {
        mj0 = fmaf(__shfl(L1v, d,     64), WL[lane][d],     mj0);
        mj1 = fmaf(__shfl(L1v, d + 1, 64), WL[lane][d + 1], mj1);
        mj2 = fmaf(__shfl(L1v, d + 2, 64), WL[lane][d + 2], mj2);
        mj3 = fmaf(__shfl(L1v, d + 3, 64), WL[lane][d + 3], mj3);
    }
    float mj  = (mj0 + mj1) + (mj2 + mj3);
    float L2v = second_chain(mj, ubv, thb, lane);
    l2bf[(size_t)lane * PB + row] = (__bf16)L2v;
}

// ---- k_mm helper macros (indices compile-time static per rule #20) ----
// 64-row tiles: each thread stages rows (tid>>4) and (tid>>4)+32.
#define ISSUE_A(T, V, W) do {                                                   \
    V = *reinterpret_cast<const f32x4*>(gA  + (T) * 64);                        \
    W = *reinterpret_cast<const f32x4*>(gA2 + (T) * 64);                        \
} while (0)
#define WRITE_A(T, V, W) do {                                                   \
    bf16x4 p_, q_;                                                              \
    p_[0]=(__bf16)V[0]; p_[1]=(__bf16)V[1]; p_[2]=(__bf16)V[2]; p_[3]=(__bf16)V[3]; \
    q_[0]=(__bf16)W[0]; q_[1]=(__bf16)W[1]; q_[2]=(__bf16)W[2]; q_[3]=(__bf16)W[3]; \
    *reinterpret_cast<bf16x4*>(As[(T) & 1] + aw_idx) = p_;                      \
    *reinterpret_cast<bf16x4*>(As[(T) & 1] + aw_idx + 32 * 64) = q_;            \
} while (0)
#define COMPUTE(T) do {                                                         \
    _Pragma("unroll")                                                           \
    for (int s_ = 0; s_ < 2; ++s_) {                                            \
        bf16x8 a_  = *reinterpret_cast<const bf16x8*>(                          \
            As[(T) & 1] + ar_row * 64 + (((4 * s_ + lg) ^ lx7) * 8));           \
        bf16x8 b0_ = *reinterpret_cast<const bf16x8*>(                          \
            Bs + br0 * 256 + (((((T) & 3) * 8 + 4 * s_ + lg) ^ lx7) * 8));      \
        bf16x8 b1_ = *reinterpret_cast<const bf16x8*>(                          \
            Bs + br1 * 256 + (((((T) & 3) * 8 + 4 * s_ + lg) ^ lx7) * 8));      \
        acc0 = __builtin_amdgcn_mfma_f32_16x16x32_bf16(a_, b0_, acc0, 0, 0, 0); \
        acc1 = __builtin_amdgcn_mfma_f32_16x16x32_bf16(a_, b1_, acc1, 0, 0, 0); \
    }                                                                           \
} while (0)
#define STAGE_B(Q) do {                                                         \
    _Pragma("unroll")                                                           \
    for (int i_ = 0; i_ < 4; ++i_) {                                            \
        const int f_ = i_ * 512 + tid;                                          \
        const int r_ = f_ >> 5, c_ = f_ & 31;                                   \
        vb[i_] = *reinterpret_cast<const bf16x8*>(                              \
            l2bf + (size_t)r_ * PB + kc + (Q) * 256 + c_ * 8);                  \
    }                                                                           \
} while (0)
#define WRITE_B() do {                                                          \
    _Pragma("unroll")                                                           \
    for (int i_ = 0; i_ < 4; ++i_) {                                            \
        const int f_ = i_ * 512 + tid;                                          \
        const int r_ = f_ >> 5, c_ = f_ & 31;                                   \
        *reinterpret_cast<bf16x8*>(Bs + r_ * 256 + ((c_ ^ (r_ & 7)) * 8)) = vb[i_]; \
    }                                                                           \
} while (0)

// Kernel 2: 64-row amortized build. Block = 64 rows x 1024-k chunk (16 tiles of
// 64 k, each tile 16 KB of A — 2x r18's bytes per barrier). 8 waves =
// rowquarter x dimhalf (16 rows x 32 dims each, 2 accs). B per 256-k quarter
// in LDS; A depth-3 paired register prefetch. Same proven r18 schedule.
__global__ __launch_bounds__(512, 6) void k_mm(
    const float* __restrict__ adj, const __bf16* __restrict__ l2bf,
    float* __restrict__ pws)
{
    __shared__ __bf16 Bs[64 * 256];          // 32 KB (one 256-k quarter of B)
    __shared__ __bf16 As[2][64 * 64];        // 2 x 8 KB A tiles -> 48 KB total
    const int tid  = threadIdx.x;
    const int lane = tid & 63;
    const int w    = tid >> 6;
    const int l15  = lane & 15;
    const int lg   = lane >> 4;
    const int lx7  = l15 & 7;
    const int rq   = w >> 1;                 // row-quarter (16 rows)
    const int dh   = w & 1;                  // dim-half (32 dims)
    const int rg   = blockIdx.x & 127;       // row-group fastest -> B stays hot
    const int kch  = blockIdx.x >> 7;        // k-chunk 0..7
    const int R0   = rg * 64;
    const int kc   = kch * 1024;

    const int arow = tid >> 4;               // staging rows arow and arow+32
    const int acol = (tid & 15) * 4;         // staging col (floats)
    const int aw_idx = arow * 64 + (((acol >> 3) ^ (arow & 7)) * 8) + (acol & 7);
    const int ar_row = rq * 16 + l15;
    const int br0 = dh * 32 + l15;
    const int br1 = dh * 32 + 16 + l15;
    const float* gA  = adj + (size_t)(R0 + arow) * NND + kc + acol;
    const float* gA2 = gA + (size_t)32 * NND;

    f32x4 va0, va0b, va1, va1b, va2, va2b;
    bf16x8 vb[4];
    f32x4 acc0 = {0.f, 0.f, 0.f, 0.f};
    f32x4 acc1 = acc0;

    // ---- prologue: B(q0) staged; A0 staged; A1..A3 in flight (depth 3)
    STAGE_B(0);
    ISSUE_A(0, va0, va0b); ISSUE_A(1, va1, va1b); ISSUE_A(2, va2, va2b);
    WRITE_B();                               // waits vb only; A loads stay in flight
    WRITE_A(0, va0, va0b);                   // waits A0 pair
    ISSUE_A(3, va0, va0b);
    __syncthreads();

    // ---- 16 tiles; B-quarter boundary after tiles 3, 7, 11 (r18 schedule)
    COMPUTE(0);                WRITE_A(1, va1, va1b);  ISSUE_A(4, va1, va1b);  __syncthreads();
    COMPUTE(1);  STAGE_B(1);   WRITE_A(2, va2, va2b);  ISSUE_A(5, va2, va2b);  __syncthreads();
    COMPUTE(2);                WRITE_A(3, va0, va0b);  ISSUE_A(6, va0, va0b);  __syncthreads();
    COMPUTE(3);  __syncthreads();  WRITE_B();
                               WRITE_A(4, va1, va1b);  ISSUE_A(7, va1, va1b);  __syncthreads();
    COMPUTE(4);                WRITE_A(5, va2, va2b);  ISSUE_A(8, va2, va2b);  __syncthreads();
    COMPUTE(5);  STAGE_B(2);   WRITE_A(6, va0, va0b);  ISSUE_A(9, va0, va0b);  __syncthreads();
    COMPUTE(6);                WRITE_A(7, va1, va1b);  ISSUE_A(10, va1, va1b); __syncthreads();
    COMPUTE(7);  __syncthreads();  WRITE_B();
                               WRITE_A(8, va2, va2b);  ISSUE_A(11, va2, va2b); __syncthreads();
    COMPUTE(8);                WRITE_A(9, va0, va0b);  ISSUE_A(12, va0, va0b); __syncthreads();
    COMPUTE(9);  STAGE_B(3);   WRITE_A(10, va1, va1b); ISSUE_A(13, va1, va1b); __syncthreads();
    COMPUTE(10);               WRITE_A(11, va2, va2b); ISSUE_A(14, va2, va2b); __syncthreads();
    COMPUTE(11); __syncthreads();  WRITE_B();
                               WRITE_A(12, va0, va0b); ISSUE_A(15, va0, va0b); __syncthreads();
    COMPUTE(12);               WRITE_A(13, va1, va1b);                         __syncthreads();
    COMPUTE(13);               WRITE_A(14, va2, va2b);                         __syncthreads();
    COMPUTE(14);               WRITE_A(15, va0, va0b);                         __syncthreads();
    COMPUTE(15);

    // ---- store partials: C/D col=l15 (within fragment), row=lg*4+i
    float* pp = pws + (size_t)kch * NND * DIM;
#pragma unroll
    for (int i = 0; i < 4; ++i) {
        const size_t grow = (size_t)(R0 + rq * 16 + lg * 4 + i);
        pp[grow * DIM + dh * 32 + l15]      = acc0[i];
        pp[grow * DIM + dh * 32 + 16 + l15] = acc1[i];
    }
}

// Kernel 3: sum 8 k-chunk partials + fused epilogue. 1 row per wave.
__global__ __launch_bounds__(256) void k_fin(
    const float* __restrict__ pws, float* __restrict__ out)
{
    const int tid  = threadIdx.x;
    const int lane = tid & 63;
    const int wave = tid >> 6;
    const int row  = blockIdx.x * 4 + wave;
    const size_t base = (size_t)row * DIM + lane;
    const size_t S = (size_t)NND * DIM;
    float hv = (((pws[base] + pws[S + base]) + (pws[2*S + base] + pws[3*S + base]))
             +  ((pws[4*S + base] + pws[5*S + base]) + (pws[6*S + base] + pws[7*S + base])));
    out[base] = epilogue_chain(hv, lane);
}

extern "C" void kernel_launch(void* const* d_in, const int* in_sizes, int n_in,
                              void* d_out, int out_size, void* d_ws, size_t ws_size,
                              hipStream_t stream)
{
    const float* x      = (const float*)d_in[0];
    const float* adj    = (const float*)d_in[1];
    const float* weight = (const float*)d_in[2];
    const float* bias   = (const float*)d_in[3];
    float* out = (float*)d_out;
    __bf16* l2bf = (__bf16*)d_ws;                          // 64 x PB bf16 = 1.33 MB
    float*  pws  = (float*)((char*)d_ws + 0x180000);       // 8 x 2 MB partials

    k_prep<<<2048, 256, 0, stream>>>(x, weight, bias, l2bf);
    k_mm<<<1024, 512, 0, stream>>>(adj, l2bf, pws);
    k_fin<<<2048, 256, 0, stream>>>(pws, out);
}

// Round 21
// 81.435 us; speedup vs baseline: 1.6210x; 1.6210x over previous
//
#include <hip/hip_runtime.h>
#include <hip/hip_bf16.h>
#include <math.h>

typedef __bf16 bf16x8 __attribute__((ext_vector_type(8)));
typedef __bf16 bf16x4 __attribute__((ext_vector_type(4)));
typedef float  f32x4  __attribute__((ext_vector_type(4)));

#define NND 8192
#define DIM 64
#define PB  10368   // l2bf padded row stride (bf16)

__device__ __forceinline__ float wsum(float v) {
#pragma unroll
    for (int m = 1; m < 64; m <<= 1) v += __shfl_xor(v, m, 64);
    return v;
}

struct SC { float sh, ch; };
__device__ __forceinline__ SC sinhcosh(float c) {
    float e  = expf(c);
    float ei = 1.0f / e;
    SC r; r.sh = 0.5f * (e - ei); r.ch = 0.5f * (e + ei);
    return r;
}

__device__ __forceinline__ float arcosh_from_n2(float n2) {
    float t = fmaxf(n2, 2.0000001e-7f);
    return logf(sqrtf(1.0f + t) + sqrtf(t));
}

__device__ __forceinline__ float tangent_chain(float xv, int lane) {
    float y   = (lane == 0) ? 0.0f : xv;
    float yn2 = wsum(y * y);
    float yn  = fmaxf(sqrtf(fmaxf(yn2, 1e-30f)), 1e-15f);
    SC s1 = sinhcosh(fminf(yn, 15.0f));
    float r   = (lane == 0) ? 0.0f : s1.sh * y / yn;
    float rn2 = wsum(r * r);
    float ynb = fmaxf(sqrtf(fmaxf(rn2, 1e-30f)), 1e-15f);
    float ac  = arcosh_from_n2(rn2);
    return (lane == 0) ? 0.0f : ac * r / ynb;
}

__device__ __forceinline__ float second_chain(float m, float ubv, float theta_b, int lane) {
    float my  = (lane == 0) ? 0.0f : m;
    float mn2 = wsum(my * my);
    float mn  = fmaxf(sqrtf(fmaxf(mn2, 1e-30f)), 1e-15f);
    SC s2 = sinhcosh(fminf(mn, 15.0f));
    float rr   = (lane == 0) ? 0.0f : s2.sh * my / mn;
    float rrn2 = wsum(rr * rr);
    float res0 = sqrtf(fmaxf(1.0f + rrn2, 1e-7f));
    float yn3   = fmaxf(sqrtf(fmaxf(rrn2, 1e-30f)), 1e-15f);
    float yhat  = (lane == 0) ? 0.0f : rr / yn3;
    float alpha = wsum(yhat * ubv);
    float w_    = ubv - alpha * (1.0f - res0) * yhat;
    float ux    = wsum(rr * w_);
    float v0    = ux / fmaxf(res0, 1e-7f);
    float vv    = (lane == 0) ? v0 : w_;
    float resv  = (lane == 0) ? res0 : rr;
    float theta = theta_b;
    SC s3 = sinhcosh(fminf(theta, 15.0f));
    float pv  = s3.ch * resv + s3.sh * vv / theta;
    float pn2 = wsum((lane == 0) ? 0.0f : pv * pv);
    float yn4 = fmaxf(sqrtf(fmaxf(pn2, 1e-30f)), 1e-15f);
    float ac4 = arcosh_from_n2(pn2);
    return (lane == 0) ? 0.0f : ac4 * pv / yn4;
}

__device__ __forceinline__ float epilogue_chain(float hv, int lane) {
    float y   = (lane == 0) ? 0.0f : hv;
    float yn2 = wsum(y * y);
    float yn  = fmaxf(sqrtf(fmaxf(yn2, 1e-30f)), 1e-15f);
    SC s1 = sinhcosh(fminf(yn, 15.0f));
    float r   = (lane == 0) ? 0.0f : s1.sh * y / yn;
    float rn2 = wsum(r * r);
    float ynb = fmaxf(sqrtf(fmaxf(rn2, 1e-30f)), 1e-15f);
    float ac  = arcosh_from_n2(rn2);
    float lgv = (lane == 0) ? 0.0f : ac * r / ynb;
    float t   = (lgv > 0.0f) ? lgv : 0.01f * lgv;
    float tn2 = wsum(t * t);
    float tn  = fmaxf(sqrtf(fmaxf(tn2, 1e-30f)), 1e-15f);
    SC s3 = sinhcosh(fminf(tn, 15.0f));
    float ov  = (lane == 0) ? 0.0f : s3.sh * t / tn;
    float on2 = wsum(ov * ov);
    float o0  = sqrtf(fmaxf(1.0f + on2, 1e-7f));
    return (lane == 0) ? o0 : ov;
}

// Kernel 1: per-row chain + 64x64 matvec; 1 row per wave. (PB layout, unchanged)
__global__ __launch_bounds__(256) void k_prep(
    const float* __restrict__ x, const float* __restrict__ weight,
    const float* __restrict__ bias, __bf16* __restrict__ l2bf)
{
    __shared__ float WL[64][65];
    const int tid  = threadIdx.x;
    const int lane = tid & 63;
    const int wave = tid >> 6;
#pragma unroll
    for (int i = 0; i < 16; ++i) {
        int idx = i * 256 + tid;
        WL[idx >> 6][idx & 63] = weight[idx];
    }
    __syncthreads();
    float ubv  = tangent_chain(bias[lane], lane);
    float nub2 = wsum(ubv * ubv);
    float thb  = fmaxf(fminf(sqrtf(fmaxf(nub2, 1e-7f)), 1e6f), 1e-15f);

    const int row = blockIdx.x * 4 + wave;
    float xv  = x[row * 64 + lane];
    float L1v = tangent_chain(xv, lane);
    float mj0 = 0.f, mj1 = 0.f, mj2 = 0.f, mj3 = 0.f;
#pragma unroll
    for (int d = 0; d < 64; d += 4) {
        mj0 = fmaf(__shfl(L1v, d,     64), WL[lane][d],     mj0);
        mj1 = fmaf(__shfl(L1v, d + 1, 64), WL[lane][d + 1], mj1);
        mj2 = fmaf(__shfl(L1v, d + 2, 64), WL[lane][d + 2], mj2);
        mj3 = fmaf(__shfl(L1v, d + 3, 64), WL[lane][d + 3], mj3);
    }
    float mj  = (mj0 + mj1) + (mj2 + mj3);
    float L2v = second_chain(mj, ubv, thb, lane);
    l2bf[(size_t)lane * PB + row] = (__bf16)L2v;
}

// ---- k_mm helper macros (indices compile-time static per rule #20) ----
#define ISSUE_A(T, V)  V = *reinterpret_cast<const f32x4*>(gA + (T) * 64);
#define WRITE_A(T, V)  do {                                                     \
    bf16x4 p_; p_[0]=(__bf16)V[0]; p_[1]=(__bf16)V[1];                          \
    p_[2]=(__bf16)V[2]; p_[3]=(__bf16)V[3];                                     \
    *reinterpret_cast<bf16x4*>(As[(T) & 1] + aw_idx) = p_;                      \
} while (0)
// COMPUTE(T): A from As[T&1]; B from slice s=T>>1 in Bs[(T>>1)&1], 128-bf16 rows.
#define COMPUTE(T) do {                                                         \
    _Pragma("unroll")                                                           \
    for (int s_ = 0; s_ < 2; ++s_) {                                            \
        bf16x8 a_ = *reinterpret_cast<const bf16x8*>(                           \
            As[(T) & 1] + ar_row * 64 + (((4 * s_ + lg) ^ lx7) * 8));           \
        bf16x8 b_ = *reinterpret_cast<const bf16x8*>(                           \
            Bs[((T) >> 1) & 1] + br_row * 128 +                                 \
            (((((T) & 1) * 8 + 4 * s_ + lg) ^ lx7) * 8));                       \
        acc = __builtin_amdgcn_mfma_f32_16x16x32_bf16(a_, b_, acc, 0, 0, 0);    \
    }                                                                           \
} while (0)
// B slice S: 64 rows x 128 bf16 = 16 KB; 2 bf16x8 loads/thread.
#define STAGE_B(S) do {                                                         \
    _Pragma("unroll")                                                           \
    for (int i_ = 0; i_ < 2; ++i_) {                                            \
        const int f_ = i_ * 512 + tid;                                          \
        const int r_ = f_ >> 4, c_ = f_ & 15;                                   \
        vb[i_] = *reinterpret_cast<const bf16x8*>(                              \
            l2bf + (size_t)r_ * PB + kc + (S) * 128 + c_ * 8);                  \
    }                                                                           \
} while (0)
#define WRITE_B(S) do {                                                         \
    _Pragma("unroll")                                                           \
    for (int i_ = 0; i_ < 2; ++i_) {                                            \
        const int f_ = i_ * 512 + tid;                                          \
        const int r_ = f_ >> 4, c_ = f_ & 15;                                   \
        *reinterpret_cast<bf16x8*>(Bs[(S) & 1] + r_ * 128 +                     \
                                   ((c_ ^ (r_ & 7)) * 8)) = vb[i_];             \
    }                                                                           \
} while (0)

// Kernel 2: r18 structure + double-buffered B slices (128 k each, 2x16 KB =
// same 32 KB as r18's single quarter). WRITE_B targets the idle B buffer, so
// the ordinary per-tile barrier orders everything — the 4 compute-empty
// boundary segments of r18 are eliminated (19 -> 17 barriers, all with MFMA).
// A depth-3 register prefetch unchanged. 40 KB LDS -> 4 blocks/CU, 32 waves.
__global__ __launch_bounds__(512, 6) void k_mm(
    const float* __restrict__ adj, const __bf16* __restrict__ l2bf,
    float* __restrict__ pws)
{
    __shared__ __bf16 Bs[2][64 * 128];       // 2 x 16 KB B slices
    __shared__ __bf16 As[2][32 * 64];        // 2 x 4 KB A tiles -> 40 KB total
    const int tid  = threadIdx.x;
    const int lane = tid & 63;
    const int w    = tid >> 6;
    const int l15  = lane & 15;
    const int lg   = lane >> 4;
    const int lx7  = l15 & 7;
    const int rh   = w >> 2;                 // row-half
    const int dq   = w & 3;                  // dim-quarter
    const int rg   = blockIdx.x & 255;       // row-group fastest -> B stays hot
    const int kch  = blockIdx.x >> 8;        // k-chunk 0..7
    const int R0   = rg * 32;
    const int kc   = kch * 1024;

    const int arow = tid >> 4;               // staging row 0..31
    const int acol = (tid & 15) * 4;         // staging col (floats)
    const int aw_idx = arow * 64 + (((acol >> 3) ^ (arow & 7)) * 8) + (acol & 7);
    const int ar_row = rh * 16 + l15;
    const int br_row = dq * 16 + l15;
    const float* gA = adj + (size_t)(R0 + arow) * NND + kc + acol;

    f32x4 va0, va1, va2;
    bf16x8 vb[2];
    f32x4 acc = {0.f, 0.f, 0.f, 0.f};

    // ---- prologue: B slice0 staged; A0 staged; A1..A3 in flight (depth 3)
    STAGE_B(0);
    ISSUE_A(0, va0); ISSUE_A(1, va1); ISSUE_A(2, va2);
    WRITE_B(0);                              // waits vb only; A loads stay in flight
    WRITE_A(0, va0);                         // waits A0
    ISSUE_A(3, va0);
    __syncthreads();

    // ---- 16 tiles; slice s=T>>1; STAGE_B(s+1) at even T, WRITE_B at odd T
    COMPUTE(0);  STAGE_B(1);  WRITE_A(1, va1);  ISSUE_A(4, va1);  __syncthreads();
    COMPUTE(1);  WRITE_B(1);  WRITE_A(2, va2);  ISSUE_A(5, va2);  __syncthreads();
    COMPUTE(2);  STAGE_B(2);  WRITE_A(3, va0);  ISSUE_A(6, va0);  __syncthreads();
    COMPUTE(3);  WRITE_B(2);  WRITE_A(4, va1);  ISSUE_A(7, va1);  __syncthreads();
    COMPUTE(4);  STAGE_B(3);  WRITE_A(5, va2);  ISSUE_A(8, va2);  __syncthreads();
    COMPUTE(5);  WRITE_B(3);  WRITE_A(6, va0);  ISSUE_A(9, va0);  __syncthreads();
    COMPUTE(6);  STAGE_B(4);  WRITE_A(7, va1);  ISSUE_A(10, va1); __syncthreads();
    COMPUTE(7);  WRITE_B(4);  WRITE_A(8, va2);  ISSUE_A(11, va2); __syncthreads();
    COMPUTE(8);  STAGE_B(5);  WRITE_A(9, va0);  ISSUE_A(12, va0); __syncthreads();
    COMPUTE(9);  WRITE_B(5);  WRITE_A(10, va1); ISSUE_A(13, va1); __syncthreads();
    COMPUTE(10); STAGE_B(6);  WRITE_A(11, va2); ISSUE_A(14, va2); __syncthreads();
    COMPUTE(11); WRITE_B(6);  WRITE_A(12, va0); ISSUE_A(15, va0); __syncthreads();
    COMPUTE(12); STAGE_B(7);  WRITE_A(13, va1);                   __syncthreads();
    COMPUTE(13); WRITE_B(7);  WRITE_A(14, va2);                   __syncthreads();
    COMPUTE(14);              WRITE_A(15, va0);                   __syncthreads();
    COMPUTE(15);

    // ---- store partials: C/D col=l15 (dim in quarter), row=lg*4+i
    float* pp = pws + (size_t)kch * NND * DIM;
#pragma unroll
    for (int i = 0; i < 4; ++i) {
        pp[(size_t)(R0 + rh * 16 + lg * 4 + i) * DIM + dq * 16 + l15] = acc[i];
    }
}

// Kernel 3: sum 8 k-chunk partials + fused epilogue. 1 row per wave.
__global__ __launch_bounds__(256) void k_fin(
    const float* __restrict__ pws, float* __restrict__ out)
{
    const int tid  = threadIdx.x;
    const int lane = tid & 63;
    const int wave = tid >> 6;
    const int row  = blockIdx.x * 4 + wave;
    const size_t base = (size_t)row * DIM + lane;
    const size_t S = (size_t)NND * DIM;
    float hv = (((pws[base] + pws[S + base]) + (pws[2*S + base] + pws[3*S + base]))
             +  ((pws[4*S + base] + pws[5*S + base]) + (pws[6*S + base] + pws[7*S + base])));
    out[base] = epilogue_chain(hv, lane);
}

extern "C" void kernel_launch(void* const* d_in, const int* in_sizes, int n_in,
                              void* d_out, int out_size, void* d_ws, size_t ws_size,
                              hipStream_t stream)
{
    const float* x      = (const float*)d_in[0];
    const float* adj    = (const float*)d_in[1];
    const float* weight = (const float*)d_in[2];
    const float* bias   = (const float*)d_in[3];
    float* out = (float*)d_out;
    __bf16* l2bf = (__bf16*)d_ws;                          // 64 x PB bf16 = 1.33 MB
    float*  pws  = (float*)((char*)d_ws + 0x180000);       // 8 x 2 MB partials

    k_prep<<<2048, 256, 0, stream>>>(x, weight, bias, l2bf);
    k_mm<<<2048, 512, 0, stream>>>(adj, l2bf, pws);
    k_fin<<<2048, 256, 0, stream>>>(pws, out);
}

// Round 22
// 78.918 us; speedup vs baseline: 1.6727x; 1.0319x over previous
//
#include <hip/hip_runtime.h>
#include <hip/hip_bf16.h>
#include <math.h>

typedef __bf16 bf16x8 __attribute__((ext_vector_type(8)));
typedef __bf16 bf16x4 __attribute__((ext_vector_type(4)));
typedef float  f32x4  __attribute__((ext_vector_type(4)));

#define NND 8192
#define DIM 64
#define PB  10368   // l2bf padded row stride (bf16)

__device__ __forceinline__ float wsum(float v) {
#pragma unroll
    for (int m = 1; m < 64; m <<= 1) v += __shfl_xor(v, m, 64);
    return v;
}

struct SC { float sh, ch; };
__device__ __forceinline__ SC sinhcosh(float c) {
    float e  = expf(c);
    float ei = 1.0f / e;
    SC r; r.sh = 0.5f * (e - ei); r.ch = 0.5f * (e + ei);
    return r;
}

__device__ __forceinline__ float arcosh_from_n2(float n2) {
    float t = fmaxf(n2, 2.0000001e-7f);
    return logf(sqrtf(1.0f + t) + sqrtf(t));
}

__device__ __forceinline__ float tangent_chain(float xv, int lane) {
    float y   = (lane == 0) ? 0.0f : xv;
    float yn2 = wsum(y * y);
    float yn  = fmaxf(sqrtf(fmaxf(yn2, 1e-30f)), 1e-15f);
    SC s1 = sinhcosh(fminf(yn, 15.0f));
    float r   = (lane == 0) ? 0.0f : s1.sh * y / yn;
    float rn2 = wsum(r * r);
    float ynb = fmaxf(sqrtf(fmaxf(rn2, 1e-30f)), 1e-15f);
    float ac  = arcosh_from_n2(rn2);
    return (lane == 0) ? 0.0f : ac * r / ynb;
}

__device__ __forceinline__ float second_chain(float m, float ubv, float theta_b, int lane) {
    float my  = (lane == 0) ? 0.0f : m;
    float mn2 = wsum(my * my);
    float mn  = fmaxf(sqrtf(fmaxf(mn2, 1e-30f)), 1e-15f);
    SC s2 = sinhcosh(fminf(mn, 15.0f));
    float rr   = (lane == 0) ? 0.0f : s2.sh * my / mn;
    float rrn2 = wsum(rr * rr);
    float res0 = sqrtf(fmaxf(1.0f + rrn2, 1e-7f));
    float yn3   = fmaxf(sqrtf(fmaxf(rrn2, 1e-30f)), 1e-15f);
    float yhat  = (lane == 0) ? 0.0f : rr / yn3;
    float alpha = wsum(yhat * ubv);
    float w_    = ubv - alpha * (1.0f - res0) * yhat;
    float ux    = wsum(rr * w_);
    float v0    = ux / fmaxf(res0, 1e-7f);
    float vv    = (lane == 0) ? v0 : w_;
    float resv  = (lane == 0) ? res0 : rr;
    float theta = theta_b;
    SC s3 = sinhcosh(fminf(theta, 15.0f));
    float pv  = s3.ch * resv + s3.sh * vv / theta;
    float pn2 = wsum((lane == 0) ? 0.0f : pv * pv);
    float yn4 = fmaxf(sqrtf(fmaxf(pn2, 1e-30f)), 1e-15f);
    float ac4 = arcosh_from_n2(pn2);
    return (lane == 0) ? 0.0f : ac4 * pv / yn4;
}

__device__ __forceinline__ float epilogue_chain(float hv, int lane) {
    float y   = (lane == 0) ? 0.0f : hv;
    float yn2 = wsum(y * y);
    float yn  = fmaxf(sqrtf(fmaxf(yn2, 1e-30f)), 1e-15f);
    SC s1 = sinhcosh(fminf(yn, 15.0f));
    float r   = (lane == 0) ? 0.0f : s1.sh * y / yn;
    float rn2 = wsum(r * r);
    float ynb = fmaxf(sqrtf(fmaxf(rn2, 1e-30f)), 1e-15f);
    float ac  = arcosh_from_n2(rn2);
    float lgv = (lane == 0) ? 0.0f : ac * r / ynb;
    float t   = (lgv > 0.0f) ? lgv : 0.01f * lgv;
    float tn2 = wsum(t * t);
    float tn  = fmaxf(sqrtf(fmaxf(tn2, 1e-30f)), 1e-15f);
    SC s3 = sinhcosh(fminf(tn, 15.0f));
    float ov  = (lane == 0) ? 0.0f : s3.sh * t / tn;
    float on2 = wsum(ov * ov);
    float o0  = sqrtf(fmaxf(1.0f + on2, 1e-7f));
    return (lane == 0) ? o0 : ov;
}

// Kernel 1: per-row chain + 64x64 matvec; 1 row per wave. Bias chain computed
// ONCE by wave 0 and broadcast via LDS (bitwise-identical values, ~25% less work).
__global__ __launch_bounds__(256) void k_prep(
    const float* __restrict__ x, const float* __restrict__ weight,
    const float* __restrict__ bias, __bf16* __restrict__ l2bf)
{
    __shared__ float WL[64][65];
    __shared__ float ub_sh[65];
    const int tid  = threadIdx.x;
    const int lane = tid & 63;
    const int wave = tid >> 6;
#pragma unroll
    for (int i = 0; i < 16; ++i) {
        int idx = i * 256 + tid;
        WL[idx >> 6][idx & 63] = weight[idx];
    }
    if (wave == 0) {
        float ub   = tangent_chain(bias[lane], lane);
        float nub2 = wsum(ub * ub);
        float th   = fmaxf(fminf(sqrtf(fmaxf(nub2, 1e-7f)), 1e6f), 1e-15f);
        ub_sh[lane] = ub;
        if (lane == 0) ub_sh[64] = th;
    }
    __syncthreads();
    const float ubv = ub_sh[lane];
    const float thb = ub_sh[64];

    const int row = blockIdx.x * 4 + wave;
    float xv  = x[row * 64 + lane];
    float L1v = tangent_chain(xv, lane);
    float mj0 = 0.f, mj1 = 0.f, mj2 = 0.f, mj3 = 0.f;
#pragma unroll
    for (int d = 0; d < 64; d += 4) {
        mj0 = fmaf(__shfl(L1v, d,     64), WL[lane][d],     mj0);
        mj1 = fmaf(__shfl(L1v, d + 1, 64), WL[lane][d + 1], mj1);
        mj2 = fmaf(__shfl(L1v, d + 2, 64), WL[lane][d + 2], mj2);
        mj3 = fmaf(__shfl(L1v, d + 3, 64), WL[lane][d + 3], mj3);
    }
    float mj  = (mj0 + mj1) + (mj2 + mj3);
    float L2v = second_chain(mj, ubv, thb, lane);
    l2bf[(size_t)lane * PB + row] = (__bf16)L2v;
}

// ---- k_mm helper macros (r18-proven, indices compile-time static) ----
#define ISSUE_A(T, V)  V = *reinterpret_cast<const f32x4*>(gA + (T) * 64);
#define WRITE_A(T, V)  do {                                                     \
    bf16x4 p_; p_[0]=(__bf16)V[0]; p_[1]=(__bf16)V[1];                          \
    p_[2]=(__bf16)V[2]; p_[3]=(__bf16)V[3];                                     \
    *reinterpret_cast<bf16x4*>(As[(T) & 1] + aw_idx) = p_;                      \
} while (0)
#define COMPUTE(T) do {                                                         \
    _Pragma("unroll")                                                           \
    for (int s_ = 0; s_ < 2; ++s_) {                                            \
        bf16x8 a_ = *reinterpret_cast<const bf16x8*>(                           \
            As[(T) & 1] + ar_row * 64 + (((4 * s_ + lg) ^ lx7) * 8));           \
        bf16x8 b_ = *reinterpret_cast<const bf16x8*>(                           \
            Bs + br_row * 256 + (((((T) & 3) * 8 + 4 * s_ + lg) ^ lx7) * 8));   \
        acc = __builtin_amdgcn_mfma_f32_16x16x32_bf16(a_, b_, acc, 0, 0, 0);    \
    }                                                                           \
} while (0)
#define STAGE_B(Q) do {                                                         \
    _Pragma("unroll")                                                           \
    for (int i_ = 0; i_ < 4; ++i_) {                                            \
        const int f_ = i_ * 512 + tid;                                          \
        const int r_ = f_ >> 5, c_ = f_ & 31;                                   \
        vb[i_] = *reinterpret_cast<const bf16x8*>(                              \
            l2bf + (size_t)r_ * PB + kc + (Q) * 256 + c_ * 8);                  \
    }                                                                           \
} while (0)
#define WRITE_B() do {                                                          \
    _Pragma("unroll")                                                           \
    for (int i_ = 0; i_ < 4; ++i_) {                                            \
        const int f_ = i_ * 512 + tid;                                          \
        const int r_ = f_ >> 5, c_ = f_ & 31;                                   \
        *reinterpret_cast<bf16x8*>(Bs + r_ * 256 + ((c_ ^ (r_ & 7)) * 8)) = vb[i_]; \
    }                                                                           \
} while (0)

// Kernel 2: r18 depth-3 duty-cycle build (measured 79.6 us total, best).
// Block = 32 rows x 1024-k chunk (16 tiles), 8 waves (rowhalf x dimquarter).
// B staged per 256-k quarter; A depth-3 register prefetch (ISSUE at T, WRITE
// at T+3). A-loads are the only steady-state VMEM ops -> reg-dep vmcnt keeps
// the FIFO never empty. 40 KB LDS -> 4 blocks/CU = 32 waves/CU.
__global__ __launch_bounds__(512, 6) void k_mm(
    const float* __restrict__ adj, const __bf16* __restrict__ l2bf,
    float* __restrict__ pws)
{
    __shared__ __bf16 Bs[64 * 256];          // 32 KB (one 256-k quarter of B)
    __shared__ __bf16 As[2][32 * 64];        // 2 x 4 KB A tiles -> 40 KB total
    const int tid  = threadIdx.x;
    const int lane = tid & 63;
    const int w    = tid >> 6;
    const int l15  = lane & 15;
    const int lg   = lane >> 4;
    const int lx7  = l15 & 7;
    const int rh   = w >> 2;                 // row-half
    const int dq   = w & 3;                  // dim-quarter
    const int rg   = blockIdx.x & 255;       // row-group fastest -> B stays hot
    const int kch  = blockIdx.x >> 8;        // k-chunk 0..7
    const int R0   = rg * 32;
    const int kc   = kch * 1024;

    const int arow = tid >> 4;               // staging row 0..31
    const int acol = (tid & 15) * 4;         // staging col (floats)
    const int aw_idx = arow * 64 + (((acol >> 3) ^ (arow & 7)) * 8) + (acol & 7);
    const int ar_row = rh * 16 + l15;
    const int br_row = dq * 16 + l15;
    const float* gA = adj + (size_t)(R0 + arow) * NND + kc + acol;

    f32x4 va0, va1, va2;
    bf16x8 vb[4];
    f32x4 acc = {0.f, 0.f, 0.f, 0.f};

    // ---- prologue: B(q0) staged; A0 staged; A1..A3 in flight (depth 3)
    STAGE_B(0);
    ISSUE_A(0, va0); ISSUE_A(1, va1); ISSUE_A(2, va2);
    WRITE_B();                               // waits vb only; A0..A2 stay in flight
    WRITE_A(0, va0);                         // waits A0
    ISSUE_A(3, va0);
    __syncthreads();

    // ---- 16 tiles; B-quarter boundary after tiles 3, 7, 11
    COMPUTE(0);                WRITE_A(1, va1);  ISSUE_A(4, va1);  __syncthreads();
    COMPUTE(1);  STAGE_B(1);   WRITE_A(2, va2);  ISSUE_A(5, va2);  __syncthreads();
    COMPUTE(2);                WRITE_A(3, va0);  ISSUE_A(6, va0);  __syncthreads();
    COMPUTE(3);  __syncthreads();  WRITE_B();
                               WRITE_A(4, va1);  ISSUE_A(7, va1);  __syncthreads();
    COMPUTE(4);                WRITE_A(5, va2);  ISSUE_A(8, va2);  __syncthreads();
    COMPUTE(5);  STAGE_B(2);   WRITE_A(6, va0);  ISSUE_A(9, va0);  __syncthreads();
    COMPUTE(6);                WRITE_A(7, va1);  ISSUE_A(10, va1); __syncthreads();
    COMPUTE(7);  __syncthreads();  WRITE_B();
                               WRITE_A(8, va2);  ISSUE_A(11, va2); __syncthreads();
    COMPUTE(8);                WRITE_A(9, va0);  ISSUE_A(12, va0); __syncthreads();
    COMPUTE(9);  STAGE_B(3);   WRITE_A(10, va1); ISSUE_A(13, va1); __syncthreads();
    COMPUTE(10);               WRITE_A(11, va2); ISSUE_A(14, va2); __syncthreads();
    COMPUTE(11); __syncthreads();  WRITE_B();
                               WRITE_A(12, va0); ISSUE_A(15, va0); __syncthreads();
    COMPUTE(12);               WRITE_A(13, va1);                   __syncthreads();
    COMPUTE(13);               WRITE_A(14, va2);                   __syncthreads();
    COMPUTE(14);               WRITE_A(15, va0);                   __syncthreads();
    COMPUTE(15);

    // ---- store partials: C/D col=l15 (dim in quarter), row=lg*4+i
    float* pp = pws + (size_t)kch * NND * DIM;
#pragma unroll
    for (int i = 0; i < 4; ++i) {
        pp[(size_t)(R0 + rh * 16 + lg * 4 + i) * DIM + dq * 16 + l15] = acc[i];
    }
}

// Kernel 3: sum 8 k-chunk partials + fused epilogue. 1 row per wave.
__global__ __launch_bounds__(256) void k_fin(
    const float* __restrict__ pws, float* __restrict__ out)
{
    const int tid  = threadIdx.x;
    const int lane = tid & 63;
    const int wave = tid >> 6;
    const int row  = blockIdx.x * 4 + wave;
    const size_t base = (size_t)row * DIM + lane;
    const size_t S = (size_t)NND * DIM;
    float hv = (((pws[base] + pws[S + base]) + (pws[2*S + base] + pws[3*S + base]))
             +  ((pws[4*S + base] + pws[5*S + base]) + (pws[6*S + base] + pws[7*S + base])));
    out[base] = epilogue_chain(hv, lane);
}

extern "C" void kernel_launch(void* const* d_in, const int* in_sizes, int n_in,
                              void* d_out, int out_size, void* d_ws, size_t ws_size,
                              hipStream_t stream)
{
    const float* x      = (const float*)d_in[0];
    const float* adj    = (const float*)d_in[1];
    const float* weight = (const float*)d_in[2];
    const float* bias   = (const float*)d_in[3];
    float* out = (float*)d_out;
    __bf16* l2bf = (__bf16*)d_ws;                          // 64 x PB bf16 = 1.33 MB
    float*  pws  = (float*)((char*)d_ws + 0x180000);       // 8 x 2 MB partials

    k_prep<<<2048, 256, 0, stream>>>(x, weight, bias, l2bf);
    k_mm<<<2048, 512, 0, stream>>>(adj, l2bf, pws);
    k_fin<<<2048, 256, 0, stream>>>(pws, out);
}